// Round 1
// baseline (120155.017 us; speedup 1.0000x reference)
//
#include <hip/hip_runtime.h>
#include <stdint.h>

// Problem constants (B,S,I,H,O) = (64, 2048, 256, 512, 256), all fp32.
#define Bn 64
#define Sn 2048
#define In 256
#define Hn 512
#define On 256
#define KS 384   // front-chain length (thread A); back = Hn - KS = 128 (thread B)

// ---------------------------------------------------------------------------
// BIT-EXACT constraint (proven R5, absmax 0.0): per output element the
// arithmetic must be exactly
//   xacc = fma-chain_{i=0..255 asc}(xs[i], Wxh[i][j]);  xw = xacc + bias_h[j]
//   hacc = fma-chain_{k=0..511 asc}(hs[k], Whh[k][j]);  u  = xw + hacc
//   h' = xla_tanh(u);   y = fma-chain_k(h[k],Why[k][o]) + bias_y[o]
// This round keeps those sequences bit-identical and replaces ONLY the
// cross-block h-exchange protocol. rocprof showed the old flag/acquire
// protocol (3 sequential acquire-spins + payload reads + vmcnt(0)-draining
// barrier + release flag) cost ~15 of the 16.4 us/step (VALUBusy 5.7%).
// New protocol: SELF-VALIDATING TAGGED WORDS. Each published h element is one
// 8B relaxed agent-scope atomic word packing (tag = step) in the high 32 bits
// and the f32 bits in the low 32. Consumers issue all needed tagged loads
// back-to-back and poll until tag == t (latencies overlap; single one-way
// visibility latency). No flags, no fences, no drain barrier, no memset
// (0xAA poison decodes to a negative tag, which never matches t >= 1).
// Slots are double-buffered by step parity; overwrite safety is transitive:
// publish(t+1) <= staged all remote t <= peers published t <= peers finished
// their stage-reads of t-1 (reads complete before barrier #0; publish is
// after barrier #1). So a polled slot can only hold tag t-2 (stale) or t.
// Partition unchanged (proven resident): 256 blocks = 64 batches x 4 slices,
// 256 threads = 128 A (384 Whh regs, chain k<384) + 128 B (256 Wxh + 128 Whh
// regs, xacc + chain k>=384 + tanh + publish). ~420 regs/thread (VGPR+AGPR)
// -> 1 wave/SIMD -> 1 block/CU, all 256 co-resident.
// ---------------------------------------------------------------------------
typedef unsigned long long u64;

__device__ __forceinline__ float xla_tanh(float x) {
    const float ax = __builtin_fabsf(x);
    float xc = fmaxf(-7.99881172180175781f, fminf(7.99881172180175781f, x));
    const float x2 = xc * xc;
    float p = fmaf(x2, -2.76076847742355e-16f, 2.00018790482477e-13f);
    p = fmaf(x2, p, -8.60467152213735e-11f);
    p = fmaf(x2, p, 5.12229709037114e-08f);
    p = fmaf(x2, p, 1.48572235717979e-05f);
    p = fmaf(x2, p, 6.37261928875436e-04f);
    p = fmaf(x2, p, 4.89352455891786e-03f);
    p = xc * p;
    float q = fmaf(x2, 1.19825839466702e-06f, 1.18534705686654e-04f);
    q = fmaf(x2, q, 2.26843463243900e-03f);
    q = fmaf(x2, q, 4.89352518554385e-03f);
    return ax < 0.0004f ? x : p / q;
}

__device__ __forceinline__ u64 pub_ld(const u64* p) {
    return __hip_atomic_load(p, __ATOMIC_RELAXED, __HIP_MEMORY_SCOPE_AGENT);
}
__device__ __forceinline__ void pub_st(u64* p, u64 v) {
    __hip_atomic_store(p, v, __ATOMIC_RELAXED, __HIP_MEMORY_SCOPE_AGENT);
}
__device__ __forceinline__ int pub_tag(u64 w) { return (int)(unsigned)(w >> 32); }
__device__ __forceinline__ float pub_val(u64 w) { return __uint_as_float((unsigned)w); }
__device__ __forceinline__ u64 pub_pack(float v, int t) {
    return ((u64)(unsigned)t << 32) | (u64)__float_as_uint(v);
}

__global__ __launch_bounds__(256, 1) void rnn_scan(const float* __restrict__ x,
                                                   const float* __restrict__ Wxh,
                                                   const float* __restrict__ Whh,
                                                   const float* __restrict__ bias_h,
                                                   u64* __restrict__ hpub,
                                                   float* __restrict__ hlast) {
    const int blk = blockIdx.x;
    const int b = blk & 63;          // batch
    const int s = blk >> 6;          // column-slice 0..3 (siblings = b mod 8 -> same XCD heuristic)
    const int tid = threadIdx.x;
    const int c = tid & 127;         // column within slice
    const bool isA = tid < 128;      // wave-uniform role split
    const int j = s * 128 + c;       // global column

    __shared__ float hs[2][Hn];      // double-buffered h (read t&1, write 1-(t&1))
    __shared__ float xs[2][In];      // double-buffered x row
    __shared__ float pacc[128];      // A->B chain-accumulator handoff

    // Weight registers (384 floats/thread, coalesced loads: lanes = consecutive j)
    float W0[KS];
    if (isA) {
#pragma unroll
        for (int k = 0; k < KS; ++k) W0[k] = Whh[(size_t)k * Hn + j];
    } else {
#pragma unroll
        for (int i = 0; i < In; ++i) W0[i] = Wxh[(size_t)i * Hn + j];
#pragma unroll
        for (int k = 0; k < 128; ++k) W0[In + k] = Whh[(size_t)(KS + k) * Hn + j];
    }
    const float bh = isA ? 0.f : bias_h[j];

    hs[0][tid] = 0.f;                          // h_0 = 0
    hs[0][tid + 256] = 0.f;
    xs[0][tid] = x[(size_t)b * Sn * In + tid]; // row 0 (256 threads = full row)
    __syncthreads();

    // Tagged publish slots: [batch][slice][parity][128 cols], u64 each.
    u64* const bpub = hpub + (size_t)b * 4 * 2 * 128;
    u64* const mypub = bpub + (size_t)s * 256;

    float hn = 0.f;

    for (int t = 0; t < Sn; ++t) {
        const int rp = t & 1;
        float xw_ = 0.f;

        if (isA) {
            // ---- stage remote h_t for slices 0,1,2 (A's chain range) ----
            if (t > 0) {
                const u64* p0 = bpub + 0 * 256 + rp * 128 + c;
                const u64* p1 = bpub + 1 * 256 + rp * 128 + c;
                const u64* p2 = bpub + 2 * 256 + rp * 128 + c;
                bool d0 = (s == 0), d1 = (s == 1), d2 = (s == 2);  // own slice is local
                u64 v0 = 0, v1 = 0, v2 = 0;
                if (!d0) v0 = pub_ld(p0);      // issue all polls back-to-back:
                if (!d1) v1 = pub_ld(p1);      // the 2-3 remote latencies overlap
                if (!d2) v2 = pub_ld(p2);
                for (;;) {
                    if (!d0 && pub_tag(v0) >= t) { hs[rp][c]       = pub_val(v0); d0 = true; }
                    if (!d1 && pub_tag(v1) >= t) { hs[rp][128 + c] = pub_val(v1); d1 = true; }
                    if (!d2 && pub_tag(v2) >= t) { hs[rp][256 + c] = pub_val(v2); d2 = true; }
                    if (d0 & d1 & d2) break;
                    if (!d0) v0 = pub_ld(p0);
                    if (!d1) v1 = pub_ld(p1);
                    if (!d2) v2 = pub_ld(p2);
                }
            }
        } else {
            // prefetch next x row (2 elems/thread), issued first to hide latency
            float xn0 = 0.f, xn1 = 0.f;
            if (t + 1 < Sn) {
                xn0 = x[((size_t)b * Sn + t + 1) * In + c];
                xn1 = x[((size_t)b * Sn + t + 1) * In + 128 + c];
            }
            // issue the slice-3 tagged poll BEFORE xacc: the 1024cy xacc chain
            // hides the first poll's latency
            const u64* p3 = bpub + 3 * 256 + rp * 128 + c;
            const bool need3 = (t > 0) && (s != 3);
            u64 v3 = 0;
            if (need3) v3 = pub_ld(p3);

            // xacc: i = 0..255, ascending (exact R5 order)
            float xa = 0.f;
            const float4* x4 = (const float4*)&xs[rp][0];
#pragma unroll
            for (int q = 0; q < In / 4; ++q) {
                float4 xv = x4[q];
                xa = fmaf(xv.x, W0[4 * q + 0], xa);
                xa = fmaf(xv.y, W0[4 * q + 1], xa);
                xa = fmaf(xv.z, W0[4 * q + 2], xa);
                xa = fmaf(xv.w, W0[4 * q + 3], xa);
            }
            xw_ = xa + bh;

            if (need3) {
                while (pub_tag(v3) < t) v3 = pub_ld(p3);
                hs[rp][KS + c] = pub_val(v3);   // slice 3 (B's chain range)
            }
            if (t + 1 < Sn) {
                xs[1 - rp][c] = xn0;
                xs[1 - rp][128 + c] = xn1;
            }
        }
        __syncthreads();   // #0: hs[rp] complete (remote staged, local from t-1)

        if (isA) {
            // hacc prefix: k = 0..383, ascending, single accumulator (exact R5 order)
            float acc = 0.f;
            const float4* h4 = (const float4*)&hs[rp][0];
#pragma unroll
            for (int q = 0; q < KS / 4; ++q) {
                float4 hv = h4[q];   // broadcast ds_read_b128
                acc = fmaf(hv.x, W0[4 * q + 0], acc);
                acc = fmaf(hv.y, W0[4 * q + 1], acc);
                acc = fmaf(hv.z, W0[4 * q + 2], acc);
                acc = fmaf(hv.w, W0[4 * q + 3], acc);
            }
            pacc[c] = acc;
        }
        __syncthreads();   // #1: pacc ready

        if (!isA) {
            // hacc suffix: k = 384..511, continuing the SAME chain
            float acc = pacc[c];
            const float4* h4 = (const float4*)&hs[rp][KS];
#pragma unroll
            for (int q = 0; q < 32; ++q) {
                float4 hv = h4[q];
                acc = fmaf(hv.x, W0[In + 4 * q + 0], acc);
                acc = fmaf(hv.y, W0[In + 4 * q + 1], acc);
                acc = fmaf(hv.z, W0[In + 4 * q + 2], acc);
                acc = fmaf(hv.w, W0[In + 4 * q + 3], acc);
            }
            const float u = xw_ + acc;        // exact R5 association
            hn = xla_tanh(u);
            hs[1 - rp][j] = hn;               // local slice for step t+1
            // publish tagged word; no fence/drain needed — the 8B word
            // self-validates at the consumer (tag and value travel together)
            if (t + 1 < Sn)
                pub_st(mypub + (size_t)(1 - rp) * 128 + c, pub_pack(hn, t + 1));
        }
        // NOTE: no third barrier — publish visibility is carried by the tag,
        // and all LDS hazards for step t+1 are covered by #0/#1.
    }

    if (!isA) hlast[(size_t)b * Hn + j] = hn;
}

// ---------------------------------------------------------------------------
// y[b][o] = fma-chain_k(h_last[b][k]*Why[k][o]) + bias_y[o]  (unchanged, R5-exact)
// ---------------------------------------------------------------------------
__global__ __launch_bounds__(256) void out_gemm(const float* __restrict__ hlast,
                                                const float* __restrict__ Why,
                                                const float* __restrict__ bias_y,
                                                float* __restrict__ y) {
    const int b = blockIdx.x, o = threadIdx.x;
    __shared__ float hs[Hn];
    hs[o] = hlast[(size_t)b * Hn + o];
    hs[o + 256] = hlast[(size_t)b * Hn + o + 256];
    __syncthreads();
    float acc = 0.0f;
#pragma unroll 8
    for (int k = 0; k < Hn; ++k)
        acc = fmaf(hs[k], Why[(size_t)k * On + o], acc);
    y[(size_t)b * On + o] = acc + bias_y[o];
}

// ---------------------------------------------------------------------------
extern "C" void kernel_launch(void* const* d_in, const int* in_sizes, int n_in,
                              void* d_out, int out_size, void* d_ws, size_t ws_size,
                              hipStream_t stream) {
    // Map inputs by size (x=33554432, Whh=262144, Wxh/Why=131072 in order,
    // bias_h=512, bias_y=256).
    const float *x = nullptr, *Wxh = nullptr, *Whh = nullptr, *Why = nullptr,
                *bias_h = nullptr, *bias_y = nullptr;
    for (int i = 0; i < n_in; ++i) {
        const float* p = (const float*)d_in[i];
        const int sz = in_sizes[i];
        if (sz == Bn * Sn * In) x = p;
        else if (sz == Hn * Hn) Whh = p;
        else if (sz == In * Hn) { if (!Wxh) Wxh = p; else Why = p; }
        else if (sz == Hn) bias_h = p;
        else if (sz == On) bias_y = p;
    }
    float* y = (float*)d_out;

    // workspace: tagged hpub (64*4*2*128 u64 = 512 KB) + hlast (128 KB).
    // No flag array and NO memset: the 0xAA re-poison decodes to a negative
    // tag in every slot, which never satisfies tag >= t for t >= 1.
    char* ws = (char*)d_ws;
    u64* hpub = (u64*)ws;
    size_t hpub_bytes = (size_t)Bn * 4 * 2 * 128 * sizeof(u64);
    float* hlast = (float*)(ws + hpub_bytes);

    rnn_scan<<<dim3(256), dim3(256), 0, stream>>>(x, Wxh, Whh, bias_h,
                                                  hpub, hlast);
    out_gemm<<<dim3(Bn), dim3(On), 0, stream>>>(hlast, Why, bias_y, y);
}